// Round 1
// baseline (3039.620 us; speedup 1.0000x reference)
//
#include <hip/hip_runtime.h>
#include <math.h>

#define D_MODEL 1024
#define NHEADS  16
#define DKH     64
#define BATCH   4
#define SEQ     2048
#define NTOK    (BATCH * SEQ)   // 8192

// ---------------- block reduce (256 threads = 4 waves) ----------------
__device__ __forceinline__ float block_reduce_sum(float v, float* sbuf) {
    #pragma unroll
    for (int off = 32; off > 0; off >>= 1)
        v += __shfl_xor(v, off, 64);
    int lane = threadIdx.x & 63;
    int wid  = threadIdx.x >> 6;
    if (lane == 0) sbuf[wid] = v;
    __syncthreads();
    float total = sbuf[0] + sbuf[1] + sbuf[2] + sbuf[3];
    __syncthreads();
    return total;
}

// ---------------- prep: column norms of z + cosh/sinh(2r) ----------------
__global__ __launch_bounds__(256) void prep_kernel(const float* __restrict__ z,
                                                   const float* __restrict__ r,
                                                   float* __restrict__ zn,
                                                   float* __restrict__ ch,
                                                   float* __restrict__ sh) {
    __shared__ float sbuf[4];
    int m = blockIdx.x;
    float s = 0.f;
    for (int k = threadIdx.x; k < D_MODEL; k += 256) {
        float zv = z[k * D_MODEL + m];
        s += zv * zv;
    }
    float tot = block_reduce_sum(s, sbuf);
    if (threadIdx.x == 0) {
        float n = fmaxf(sqrtf(tot), 1e-15f);
        zn[m] = n;
        float tc = 2.f * r[m];   // c_sqrt = 1
        ch[m] = coshf(tc);
        sh[m] = sinhf(tc);
    }
}

// ---------------- fp32 GEMM: C[N,M] = A[N,K] @ B (+bias) ----------------
// BT=0: B is [K,M] row-major (x @ z).  BT=1: B is [M,K] row-major (x @ w^T).
template<int BT>
__global__ __launch_bounds__(256) void gemm_f32(const float* __restrict__ A,
                                                const float* __restrict__ Bm,
                                                const float* __restrict__ bias,
                                                float* __restrict__ Cc) {
    const int K = 1024, M = 1024;
    __shared__ float As[16][68];
    __shared__ float Bs[16][68];
    int tid = threadIdx.x;
    int tx = tid & 15, ty = tid >> 4;
    int m0 = blockIdx.y * 64;   // N-dim block (rows)
    int n0 = blockIdx.x * 64;   // M-dim block (cols)
    float acc[4][4] = {};

    int lr  = tid >> 2;         // 0..63
    int lk4 = (tid & 3) * 4;    // 0,4,8,12
    int bkk = tid >> 4;         // 0..15
    int bj4 = (tid & 15) * 4;   // 0..60

    for (int k0 = 0; k0 < K; k0 += 16) {
        float4 av = *(const float4*)&A[(size_t)(m0 + lr) * K + k0 + lk4];
        As[lk4 + 0][lr] = av.x;
        As[lk4 + 1][lr] = av.y;
        As[lk4 + 2][lr] = av.z;
        As[lk4 + 3][lr] = av.w;
        if (BT == 0) {
            float4 bv = *(const float4*)&Bm[(size_t)(k0 + bkk) * M + n0 + bj4];
            *(float4*)&Bs[bkk][bj4] = bv;
        } else {
            float4 bv = *(const float4*)&Bm[(size_t)(n0 + lr) * K + k0 + lk4];
            Bs[lk4 + 0][lr] = bv.x;
            Bs[lk4 + 1][lr] = bv.y;
            Bs[lk4 + 2][lr] = bv.z;
            Bs[lk4 + 3][lr] = bv.w;
        }
        __syncthreads();
        #pragma unroll
        for (int kk = 0; kk < 16; ++kk) {
            float4 a4 = *(const float4*)&As[kk][ty * 4];
            float4 b4 = *(const float4*)&Bs[kk][tx * 4];
            float avr[4] = {a4.x, a4.y, a4.z, a4.w};
            float bvr[4] = {b4.x, b4.y, b4.z, b4.w};
            #pragma unroll
            for (int i = 0; i < 4; ++i)
                #pragma unroll
                for (int j = 0; j < 4; ++j)
                    acc[i][j] += avr[i] * bvr[j];
        }
        __syncthreads();
    }
    #pragma unroll
    for (int i = 0; i < 4; ++i) {
        int row = m0 + ty * 4 + i;
        #pragma unroll
        for (int j = 0; j < 4; ++j) {
            int col = n0 + tx * 4 + j;
            float v = acc[i][j];
            if (bias) v += bias[col];
            Cc[(size_t)row * M + col] = v;
        }
    }
}

// ---------------- Poincare epilogue: P (pre-activation) -> ball point, in place ----
__global__ __launch_bounds__(256) void poincare_epilogue(const float* __restrict__ x,
                                                         float* __restrict__ P,
                                                         const float* __restrict__ zn,
                                                         const float* __restrict__ ch,
                                                         const float* __restrict__ sh) {
    __shared__ float sbuf[4];
    int n = blockIdx.x;
    const float* xr = x + (size_t)n * D_MODEL;
    float s = 0.f;
    #pragma unroll
    for (int i = 0; i < 4; ++i) {
        float xv = xr[threadIdx.x + 256 * i];
        s += xv * xv;
    }
    float xn2 = block_reduce_sum(s, sbuf);
    float lam = 2.f / (1.f - xn2);          // x strictly inside ball (max norm 0.7)
    float w[4];
    float wn2 = 0.f;
    #pragma unroll
    for (int i = 0; i < 4; ++i) {
        int o = threadIdx.x + 256 * i;
        float zno = zn[o];
        float inner = P[(size_t)n * D_MODEL + o] / zno;
        float t = lam * inner * ch[o] - (lam - 1.f) * sh[o];
        float v = 2.f * zno * asinhf(t);
        w[i] = sinhf(v);
        wn2 += w[i] * w[i];
    }
    wn2 = block_reduce_sum(wn2, sbuf);
    float invd = 1.f / (1.f + sqrtf(1.f + wn2));
    #pragma unroll
    for (int i = 0; i < 4; ++i) {
        int o = threadIdx.x + 256 * i;
        P[(size_t)n * D_MODEL + o] = w[i] * invd;
    }
}

// ---------------- attention: one thread per q-row; scores bounded by 1/8 ------
// |Q|,|K| < 1 (Poincare ball) => |Q_h . K_h| / 8 <= 1/8 => plain exp, no max-track.
#define KT 64
__global__ __launch_bounds__(256) void attn_kernel(const float* __restrict__ Q,
                                                   const float* __restrict__ Kt,
                                                   const float* __restrict__ Vt,
                                                   float* __restrict__ Out) {
    __shared__ float4 Ks[KT][16];
    __shared__ float4 Vs[KT][16];
    int tid  = threadIdx.x;
    int qrow = blockIdx.x * 256 + tid;
    int h = blockIdx.y, b = blockIdx.z;
    const float* qptr = Q + ((size_t)(b * SEQ + qrow)) * D_MODEL + h * DKH;
    float4 q4[16];
    #pragma unroll
    for (int i = 0; i < 16; ++i) {
        float4 v = *(const float4*)&qptr[i * 4];
        q4[i].x = v.x * 0.125f;  // fold 1/sqrt(64) into q
        q4[i].y = v.y * 0.125f;
        q4[i].z = v.z * 0.125f;
        q4[i].w = v.w * 0.125f;
    }
    float4 num[16];
    #pragma unroll
    for (int i = 0; i < 16; ++i) { num[i].x = 0.f; num[i].y = 0.f; num[i].z = 0.f; num[i].w = 0.f; }
    float den = 0.f;
    const float* kbase = Kt + ((size_t)(b * SEQ)) * D_MODEL + h * DKH;
    const float* vbase = Vt + ((size_t)(b * SEQ)) * D_MODEL + h * DKH;

    for (int kt0 = 0; kt0 < SEQ; kt0 += KT) {
        #pragma unroll
        for (int i = 0; i < 4; ++i) {
            int idx = tid + 256 * i;   // 0..1023
            int row = idx >> 4;
            int c   = idx & 15;
            Ks[row][c] = *(const float4*)&kbase[(size_t)(kt0 + row) * D_MODEL + c * 4];
            Vs[row][c] = *(const float4*)&vbase[(size_t)(kt0 + row) * D_MODEL + c * 4];
        }
        __syncthreads();
        for (int kk = 0; kk < KT; ++kk) {
            float s = 0.f;
            #pragma unroll
            for (int i = 0; i < 16; ++i) {
                float4 kv = Ks[kk][i];
                s += q4[i].x * kv.x + q4[i].y * kv.y + q4[i].z * kv.z + q4[i].w * kv.w;
            }
            float p = __expf(s);
            den += p;
            #pragma unroll
            for (int i = 0; i < 16; ++i) {
                float4 vv = Vs[kk][i];
                num[i].x += p * vv.x;
                num[i].y += p * vv.y;
                num[i].z += p * vv.z;
                num[i].w += p * vv.w;
            }
        }
        __syncthreads();
    }
    float inv = 1.f / den;
    float* optr = Out + ((size_t)(b * SEQ + qrow)) * D_MODEL + h * DKH;
    #pragma unroll
    for (int i = 0; i < 16; ++i) {
        float4 o;
        o.x = num[i].x * inv; o.y = num[i].y * inv;
        o.z = num[i].z * inv; o.w = num[i].w * inv;
        *(float4*)&optr[i * 4] = o;
    }
}

extern "C" void kernel_launch(void* const* d_in, const int* in_sizes, int n_in,
                              void* d_out, int out_size, void* d_ws, size_t ws_size,
                              hipStream_t stream) {
    const float* x   = (const float*)d_in[0];
    const float* z_q = (const float*)d_in[1];
    const float* b_q = (const float*)d_in[2];
    const float* z_k = (const float*)d_in[3];
    const float* b_k = (const float*)d_in[4];
    const float* w_v = (const float*)d_in[5];
    const float* b_v = (const float*)d_in[6];
    float* out = (float*)d_out;
    float* ws  = (float*)d_ws;

    float* Q   = ws;
    float* Kb  = ws + (size_t)NTOK * D_MODEL;
    float* Vb  = ws + 2 * (size_t)NTOK * D_MODEL;
    float* aux = ws + 3 * (size_t)NTOK * D_MODEL;
    float* znq = aux;
    float* chq = aux + 1024;
    float* shq = aux + 2048;
    float* znk = aux + 3072;
    float* chk = aux + 4096;
    float* shk = aux + 5120;

    prep_kernel<<<dim3(1024), 256, 0, stream>>>(z_q, b_q, znq, chq, shq);
    prep_kernel<<<dim3(1024), 256, 0, stream>>>(z_k, b_k, znk, chk, shk);

    gemm_f32<0><<<dim3(16, 128), 256, 0, stream>>>(x, z_q, nullptr, Q);
    gemm_f32<0><<<dim3(16, 128), 256, 0, stream>>>(x, z_k, nullptr, Kb);
    gemm_f32<1><<<dim3(16, 128), 256, 0, stream>>>(x, w_v, b_v, Vb);

    poincare_epilogue<<<dim3(NTOK), 256, 0, stream>>>(x, Q,  znq, chq, shq);
    poincare_epilogue<<<dim3(NTOK), 256, 0, stream>>>(x, Kb, znk, chk, shk);

    attn_kernel<<<dim3(SEQ / 256, NHEADS, BATCH), 256, 0, stream>>>(Q, Kb, Vb, out);
}

// Round 2
// 1052.764 us; speedup vs baseline: 2.8873x; 2.8873x over previous
//
#include <hip/hip_runtime.h>
#include <hip/hip_bf16.h>
#include <math.h>

#define D_MODEL 1024
#define NHEADS  16
#define DKH     64
#define BATCH   4
#define SEQ     2048
#define NTOK    (BATCH * SEQ)   // 8192
#define NELEM   ((size_t)NTOK * D_MODEL)  // 8388608

typedef __bf16 v8bf __attribute__((ext_vector_type(8)));
typedef float  v4f  __attribute__((ext_vector_type(4)));

__device__ __forceinline__ v8bf ld_bf16x8(const ushort* p) {
    union { uint4 u; v8bf b; } cv;
    cv.u = *(const uint4*)p;
    return cv.b;
}
__device__ __forceinline__ ushort f2bf(float f) {
    __hip_bfloat16 h = __float2bfloat16(f);
    return *(ushort*)&h;
}

// ---------------- block reduce (256 threads = 4 waves) ----------------
__device__ __forceinline__ float block_reduce_sum(float v, float* sbuf) {
    #pragma unroll
    for (int off = 32; off > 0; off >>= 1)
        v += __shfl_xor(v, off, 64);
    int lane = threadIdx.x & 63;
    int wid  = threadIdx.x >> 6;
    if (lane == 0) sbuf[wid] = v;
    __syncthreads();
    float total = sbuf[0] + sbuf[1] + sbuf[2] + sbuf[3];
    __syncthreads();
    return total;
}

// ---------------- prep: column norms of z + cosh/sinh(2r) ----------------
__global__ __launch_bounds__(256) void prep_kernel(const float* __restrict__ z,
                                                   const float* __restrict__ r,
                                                   float* __restrict__ zn,
                                                   float* __restrict__ ch,
                                                   float* __restrict__ sh) {
    __shared__ float sbuf[4];
    int m = blockIdx.x;
    float s = 0.f;
    for (int k = threadIdx.x; k < D_MODEL; k += 256) {
        float zv = z[k * D_MODEL + m];
        s += zv * zv;
    }
    float tot = block_reduce_sum(s, sbuf);
    if (threadIdx.x == 0) {
        float n = fmaxf(sqrtf(tot), 1e-15f);
        zn[m] = n;
        float tc = 2.f * r[m];   // c_sqrt = 1
        ch[m] = coshf(tc);
        sh[m] = sinhf(tc);
    }
}

// ---------------- fp32 GEMM: C[N,M] = A[N,K] @ B (+bias) ----------------
// BT=0: B is [K,M] row-major (x @ z).  BT=1: B is [M,K] row-major (x @ w^T).
// BF16OUT=1: write ushort bf16, else float.
template<int BT, int BF16OUT>
__global__ __launch_bounds__(256) void gemm_f32(const float* __restrict__ A,
                                                const float* __restrict__ Bm,
                                                const float* __restrict__ bias,
                                                void* __restrict__ Cc) {
    const int K = 1024, M = 1024;
    __shared__ float As[16][68];
    __shared__ float Bs[16][68];
    int tid = threadIdx.x;
    int tx = tid & 15, ty = tid >> 4;
    int m0 = blockIdx.y * 64;   // rows
    int n0 = blockIdx.x * 64;   // cols
    float acc[4][4] = {};

    int lr  = tid >> 2;
    int lk4 = (tid & 3) * 4;
    int bkk = tid >> 4;
    int bj4 = (tid & 15) * 4;

    for (int k0 = 0; k0 < K; k0 += 16) {
        float4 av = *(const float4*)&A[(size_t)(m0 + lr) * K + k0 + lk4];
        As[lk4 + 0][lr] = av.x;
        As[lk4 + 1][lr] = av.y;
        As[lk4 + 2][lr] = av.z;
        As[lk4 + 3][lr] = av.w;
        if (BT == 0) {
            float4 bv = *(const float4*)&Bm[(size_t)(k0 + bkk) * M + n0 + bj4];
            *(float4*)&Bs[bkk][bj4] = bv;
        } else {
            float4 bv = *(const float4*)&Bm[(size_t)(n0 + lr) * K + k0 + lk4];
            Bs[lk4 + 0][lr] = bv.x;
            Bs[lk4 + 1][lr] = bv.y;
            Bs[lk4 + 2][lr] = bv.z;
            Bs[lk4 + 3][lr] = bv.w;
        }
        __syncthreads();
        #pragma unroll
        for (int kk = 0; kk < 16; ++kk) {
            float4 a4 = *(const float4*)&As[kk][ty * 4];
            float4 b4 = *(const float4*)&Bs[kk][tx * 4];
            float avr[4] = {a4.x, a4.y, a4.z, a4.w};
            float bvr[4] = {b4.x, b4.y, b4.z, b4.w};
            #pragma unroll
            for (int i = 0; i < 4; ++i)
                #pragma unroll
                for (int j = 0; j < 4; ++j)
                    acc[i][j] += avr[i] * bvr[j];
        }
        __syncthreads();
    }
    #pragma unroll
    for (int i = 0; i < 4; ++i) {
        int row = m0 + ty * 4 + i;
        #pragma unroll
        for (int j = 0; j < 4; ++j) {
            int col = n0 + tx * 4 + j;
            float v = acc[i][j];
            if (bias) v += bias[col];
            if (BF16OUT)
                ((ushort*)Cc)[(size_t)row * M + col] = f2bf(v);
            else
                ((float*)Cc)[(size_t)row * M + col] = v;
        }
    }
}

// ---------------- Poincare epilogue: P fp32 -> ball point, bf16 out ----------
__global__ __launch_bounds__(256) void poincare_epilogue(const float* __restrict__ x,
                                                         const float* __restrict__ P,
                                                         const float* __restrict__ zn,
                                                         const float* __restrict__ ch,
                                                         const float* __restrict__ sh,
                                                         ushort* __restrict__ outb,
                                                         float oscale) {
    __shared__ float sbuf[4];
    int n = blockIdx.x;
    const float* xr = x + (size_t)n * D_MODEL;
    float s = 0.f;
    #pragma unroll
    for (int i = 0; i < 4; ++i) {
        float xv = xr[threadIdx.x + 256 * i];
        s += xv * xv;
    }
    float xn2 = block_reduce_sum(s, sbuf);
    float lam = 2.f / (1.f - xn2);
    float w[4];
    float wn2 = 0.f;
    #pragma unroll
    for (int i = 0; i < 4; ++i) {
        int o = threadIdx.x + 256 * i;
        float zno = zn[o];
        float inner = P[(size_t)n * D_MODEL + o] / zno;
        float t = lam * inner * ch[o] - (lam - 1.f) * sh[o];
        float v = 2.f * zno * asinhf(t);
        w[i] = sinhf(v);
        wn2 += w[i] * w[i];
    }
    wn2 = block_reduce_sum(wn2, sbuf);
    float invd = 1.f / (1.f + sqrtf(1.f + wn2));
    #pragma unroll
    for (int i = 0; i < 4; ++i) {
        int o = threadIdx.x + 256 * i;
        outb[(size_t)n * D_MODEL + o] = f2bf(w[i] * invd * oscale);
    }
}

// ---------------- MFMA attention --------------------------------------------
// Scores bounded: |q.k|/8 <= 1/8 (Poincare ball) => plain exp, fp32 den/O.
// Block: 4 waves, 64 q-rows (16/wave), one (b,h). KV tiles of 64.
// mfma_f32_16x16x32_bf16 layouts:
//   A[16][32]: lane l holds row l&15, k = 8*(l>>4)+i  (i=0..7, contiguous)
//   B[32][16]: lane l holds col l&15, k = 8*(l>>4)+i
//   D[16][16]: lane l holds col l&15, row = 4*(l>>4)+reg   [m89-verified]
__global__ __launch_bounds__(256) void attn_mfma(const ushort* __restrict__ Qb,
                                                 const ushort* __restrict__ Kb,
                                                 const ushort* __restrict__ Vb,
                                                 float* __restrict__ Out) {
    __shared__ ushort Klds[64 * 64];      // [key][dk], byte ^= (key&7)<<4
    __shared__ ushort Vlds[64 * 64];      // [dk][key], byte ^= (((dk>>3)^dk)&7)<<4
    __shared__ ushort Plds[4][16 * 64];   // per-wave [r][key], byte ^= (r&7)<<4

    int tid = threadIdx.x;
    int w = tid >> 6, l = tid & 63;
    int lr = l & 15, lg = l >> 4;
    int h = blockIdx.y, b = blockIdx.z;
    size_t headoff = (size_t)b * SEQ * D_MODEL + h * DKH;

    // Q fragments (scale 1/8 folded in at epilogue)
    const ushort* qp = Qb + headoff + (size_t)(blockIdx.x * 64 + w * 16 + lr) * D_MODEL;
    v8bf qa0 = ld_bf16x8(qp + lg * 8);
    v8bf qa1 = ld_bf16x8(qp + 32 + lg * 8);

    v4f o[4];
    float den[4];
    #pragma unroll
    for (int i = 0; i < 4; ++i) { o[i] = (v4f){0.f, 0.f, 0.f, 0.f}; den[i] = 0.f; }

    for (int kv0 = 0; kv0 < SEQ; kv0 += 64) {
        // ---- stage K row-major + V transposed, both bf16 + swizzle ----
        #pragma unroll
        for (int i = 0; i < 2; ++i) {
            int idx = tid + 256 * i;
            int key = idx >> 3, c8 = idx & 7;
            uint4 kv = *(const uint4*)(Kb + headoff + (size_t)(kv0 + key) * D_MODEL + c8 * 8);
            *(uint4*)((char*)Klds + key * 128 + ((c8 * 16) ^ ((key & 7) << 4))) = kv;
            uint4 vv = *(const uint4*)(Vb + headoff + (size_t)(kv0 + key) * D_MODEL + c8 * 8);
            uint vals[4] = {vv.x, vv.y, vv.z, vv.w};
            #pragma unroll
            for (int j = 0; j < 8; ++j) {
                int dk = c8 * 8 + j;
                ushort u = (ushort)(vals[j >> 1] >> ((j & 1) * 16));
                int s = ((dk >> 3) ^ dk) & 7;
                *(ushort*)((char*)Vlds + dk * 128 + ((key * 2) ^ (s << 4))) = u;
            }
        }
        __syncthreads();

        // ---- QK^T: S[16 q][64 keys] ----
        v4f sc[4];
        #pragma unroll
        for (int i = 0; i < 4; ++i) sc[i] = (v4f){0.f, 0.f, 0.f, 0.f};
        #pragma unroll
        for (int f = 0; f < 2; ++f) {
            v8bf qa = f ? qa1 : qa0;
            #pragma unroll
            for (int sub = 0; sub < 4; ++sub) {
                int key = sub * 16 + lr;
                v8bf kb = *(const v8bf*)((char*)Klds + key * 128 +
                                         ((f * 64 + lg * 16) ^ ((key & 7) << 4)));
                sc[sub] = __builtin_amdgcn_mfma_f32_16x16x32_bf16(qa, kb, sc[sub], 0, 0, 0);
            }
        }

        // ---- exp (no max needed), den accum, P -> LDS (bf16) ----
        #pragma unroll
        for (int sub = 0; sub < 4; ++sub) {
            #pragma unroll
            for (int reg = 0; reg < 4; ++reg) {
                float p = __expf(sc[sub][reg]);
                den[reg] += p;
                int r = lg * 4 + reg;
                int key = sub * 16 + lr;
                *(ushort*)((char*)&Plds[w][0] + r * 128 + ((key * 2) ^ ((r & 7) << 4))) = f2bf(p);
            }
        }

        // ---- PV: O[16 q][64 dk] += P * V ----
        #pragma unroll
        for (int f = 0; f < 2; ++f) {
            v8bf pa = *(const v8bf*)((char*)&Plds[w][0] + lr * 128 +
                                     ((f * 64 + lg * 16) ^ ((lr & 7) << 4)));
            #pragma unroll
            for (int sub = 0; sub < 4; ++sub) {
                int dk = sub * 16 + lr;
                int s = ((dk >> 3) ^ dk) & 7;
                v8bf vbf = *(const v8bf*)((char*)Vlds + dk * 128 +
                                          ((f * 64 + lg * 16) ^ (s << 4)));
                o[sub] = __builtin_amdgcn_mfma_f32_16x16x32_bf16(pa, vbf, o[sub], 0, 0, 0);
            }
        }
        __syncthreads();
    }

    // ---- reduce den across the 16-lane col groups, normalize, store ----
    #pragma unroll
    for (int m = 1; m < 16; m <<= 1) {
        #pragma unroll
        for (int reg = 0; reg < 4; ++reg)
            den[reg] += __shfl_xor(den[reg], m, 64);
    }
    size_t obase = (size_t)b * SEQ * D_MODEL +
                   (size_t)(blockIdx.x * 64 + w * 16 + lg * 4) * D_MODEL + h * DKH;
    #pragma unroll
    for (int reg = 0; reg < 4; ++reg) {
        float inv = 1.f / den[reg];
        #pragma unroll
        for (int sub = 0; sub < 4; ++sub)
            Out[obase + (size_t)reg * D_MODEL + sub * 16 + lr] = o[sub][reg] * inv;
    }
}

extern "C" void kernel_launch(void* const* d_in, const int* in_sizes, int n_in,
                              void* d_out, int out_size, void* d_ws, size_t ws_size,
                              hipStream_t stream) {
    const float* x   = (const float*)d_in[0];
    const float* z_q = (const float*)d_in[1];
    const float* b_q = (const float*)d_in[2];
    const float* z_k = (const float*)d_in[3];
    const float* b_k = (const float*)d_in[4];
    const float* w_v = (const float*)d_in[5];
    const float* b_v = (const float*)d_in[6];
    float* out = (float*)d_out;

    // ws layout: Pf fp32 (32MB, reused Q then K) | Qb | Kb | Vb bf16 (16MB each) | aux
    float*  Pf  = (float*)d_ws;
    ushort* Qb  = (ushort*)(Pf + NELEM);
    ushort* Kb  = Qb + NELEM;
    ushort* Vb  = Kb + NELEM;
    float*  aux = (float*)(Vb + NELEM);
    float* znq = aux;        float* chq = aux + 1024; float* shq = aux + 2048;
    float* znk = aux + 3072; float* chk = aux + 4096; float* shk = aux + 5120;

    prep_kernel<<<dim3(1024), 256, 0, stream>>>(z_q, b_q, znq, chq, shq);
    prep_kernel<<<dim3(1024), 256, 0, stream>>>(z_k, b_k, znk, chk, shk);

    // Q chain (scale 1/8 folded into bf16 Q)
    gemm_f32<0, 0><<<dim3(16, 128), 256, 0, stream>>>(x, z_q, nullptr, Pf);
    poincare_epilogue<<<dim3(NTOK), 256, 0, stream>>>(x, Pf, znq, chq, shq, Qb, 0.125f);
    // K chain (reuses Pf; same-stream ordering makes this safe)
    gemm_f32<0, 0><<<dim3(16, 128), 256, 0, stream>>>(x, z_k, nullptr, Pf);
    poincare_epilogue<<<dim3(NTOK), 256, 0, stream>>>(x, Pf, znk, chk, shk, Kb, 1.0f);
    // V chain: fp32 GEMM, bf16 out
    gemm_f32<1, 1><<<dim3(16, 128), 256, 0, stream>>>(x, w_v, b_v, Vb);

    attn_mfma<<<dim3(SEQ / 64, NHEADS, BATCH), 256, 0, stream>>>(Qb, Kb, Vb, out);
}

// Round 3
// 426.806 us; speedup vs baseline: 7.1218x; 2.4666x over previous
//
#include <hip/hip_runtime.h>
#include <hip/hip_bf16.h>
#include <math.h>

#define D_MODEL 1024
#define NHEADS  16
#define DKH     64
#define BATCH   4
#define SEQ     2048
#define NTOK    (BATCH * SEQ)   // 8192
#define NELEM   ((size_t)NTOK * D_MODEL)  // 8388608

typedef __bf16 v8bf __attribute__((ext_vector_type(8)));
typedef float  v4f  __attribute__((ext_vector_type(4)));

__device__ __forceinline__ v8bf ld_bf16x8(const ushort* p) {
    union { uint4 u; v8bf b; } cv;
    cv.u = *(const uint4*)p;
    return cv.b;
}
__device__ __forceinline__ ushort f2bf(float f) {
    __hip_bfloat16 h = __float2bfloat16(f);
    return *(ushort*)&h;
}

#define GLOAD_LDS16(gsrc, ldst)                                            \
    __builtin_amdgcn_global_load_lds(                                      \
        (const __attribute__((address_space(1))) void*)(gsrc),             \
        (__attribute__((address_space(3))) void*)(ldst), 16, 0, 0)

// ---------------- block reduce (256 threads = 4 waves) ----------------
__device__ __forceinline__ float block_reduce_sum(float v, float* sbuf) {
    #pragma unroll
    for (int off = 32; off > 0; off >>= 1)
        v += __shfl_xor(v, off, 64);
    int lane = threadIdx.x & 63;
    int wid  = threadIdx.x >> 6;
    if (lane == 0) sbuf[wid] = v;
    __syncthreads();
    float total = sbuf[0] + sbuf[1] + sbuf[2] + sbuf[3];
    __syncthreads();
    return total;
}

// ---------------- prep: column norms of z + cosh/sinh(2r) ----------------
__global__ __launch_bounds__(256) void prep_kernel(const float* __restrict__ z,
                                                   const float* __restrict__ r,
                                                   float* __restrict__ zn,
                                                   float* __restrict__ ch,
                                                   float* __restrict__ sh) {
    __shared__ float sbuf[4];
    int m = blockIdx.x;
    float s = 0.f;
    for (int k = threadIdx.x; k < D_MODEL; k += 256) {
        float zv = z[k * D_MODEL + m];
        s += zv * zv;
    }
    float tot = block_reduce_sum(s, sbuf);
    if (threadIdx.x == 0) {
        float n = fmaxf(sqrtf(tot), 1e-15f);
        zn[m] = n;
        float tc = 2.f * r[m];   // c_sqrt = 1
        ch[m] = coshf(tc);
        sh[m] = sinhf(tc);
    }
}

// ---------------- casts ----------------
__global__ __launch_bounds__(256) void cast_bf16(const float* __restrict__ in,
                                                 ushort* __restrict__ out) {
    size_t i = ((size_t)blockIdx.x * 256 + threadIdx.x) * 8;
    float4 a = *(const float4*)(in + i);
    float4 b = *(const float4*)(in + i + 4);
    ushort u[8] = {f2bf(a.x), f2bf(a.y), f2bf(a.z), f2bf(a.w),
                   f2bf(b.x), f2bf(b.y), f2bf(b.z), f2bf(b.w)};
    *(uint4*)(out + i) = *(uint4*)u;
}

// zT[m][k] = z[k][m], 1024x1024, fp32 -> bf16
__global__ __launch_bounds__(256) void cast_transpose_bf16(const float* __restrict__ z,
                                                           ushort* __restrict__ zT) {
    __shared__ float tile[64][65];
    int t = threadIdx.x;
    int k0 = blockIdx.y * 64, m0 = blockIdx.x * 64;
    #pragma unroll
    for (int i = 0; i < 4; ++i) {
        int r = (t >> 4) + 16 * i;
        int c = (t & 15) * 4;
        float4 v = *(const float4*)&z[(size_t)(k0 + r) * D_MODEL + m0 + c];
        tile[r][c + 0] = v.x; tile[r][c + 1] = v.y;
        tile[r][c + 2] = v.z; tile[r][c + 3] = v.w;
    }
    __syncthreads();
    #pragma unroll
    for (int i = 0; i < 2; ++i) {
        int idx = t + 256 * i;
        int r = idx >> 3;        // m-local
        int c8 = idx & 7;        // k-chunk
        ushort u[8];
        #pragma unroll
        for (int j = 0; j < 8; ++j)
            u[j] = f2bf(tile[c8 * 8 + j][r]);
        *(uint4*)&zT[(size_t)(m0 + r) * D_MODEL + k0 + c8 * 8] = *(uint4*)u;
    }
}

// ---------------- bf16 MFMA GEMM: C[8192,1024] = A @ Bt^T (+bias) ------------
// A [8192][1024] bf16 row-major, Bt [1024][1024] bf16 row-major (Bt[n][k]).
// m97 structure: 128x128 tile, BK=64, 4 waves (2x2 of 64x64), global_load_lds.
template<int BF16OUT>
__global__ __launch_bounds__(256) void gemm_bf16(const ushort* __restrict__ A,
                                                 const ushort* __restrict__ Bt,
                                                 const float* __restrict__ bias,
                                                 void* __restrict__ Cc) {
    const int K = 1024, N = 1024;
    __shared__ ushort As[128][64];   // 16KB
    __shared__ ushort Bs[128][64];   // 16KB
    int tid = threadIdx.x;
    int w = tid >> 6, l = tid & 63;
    int lr = l & 15, lg = l >> 4;
    int wr = w >> 1, wc = w & 1;
    int m0 = blockIdx.y * 128;
    int n0 = blockIdx.x * 128;

    v4f acc[4][4];
    #pragma unroll
    for (int i = 0; i < 4; ++i)
        #pragma unroll
        for (int j = 0; j < 4; ++j)
            acc[i][j] = (v4f){0.f, 0.f, 0.f, 0.f};

    int srow = w * 32 + (l >> 3);      // staging row base (per 8-row issue)
    int scol = (l & 7) * 8;            // staging k-offset (ushorts)

    for (int k0 = 0; k0 < K; k0 += 64) {
        #pragma unroll
        for (int j = 0; j < 4; ++j) {
            GLOAD_LDS16(A  + (size_t)(m0 + srow + j * 8) * K + k0 + scol,
                        &As[w * 32 + j * 8][0]);
            GLOAD_LDS16(Bt + (size_t)(n0 + srow + j * 8) * K + k0 + scol,
                        &Bs[w * 32 + j * 8][0]);
        }
        __syncthreads();
        #pragma unroll
        for (int kk = 0; kk < 2; ++kk) {
            v8bf av[4], bv[4];
            #pragma unroll
            for (int i = 0; i < 4; ++i)
                av[i] = *(const v8bf*)&As[wr * 64 + i * 16 + lr][kk * 32 + lg * 8];
            #pragma unroll
            for (int j = 0; j < 4; ++j)
                bv[j] = *(const v8bf*)&Bs[wc * 64 + j * 16 + lr][kk * 32 + lg * 8];
            #pragma unroll
            for (int i = 0; i < 4; ++i)
                #pragma unroll
                for (int j = 0; j < 4; ++j)
                    acc[i][j] = __builtin_amdgcn_mfma_f32_16x16x32_bf16(av[i], bv[j], acc[i][j], 0, 0, 0);
        }
        __syncthreads();
    }

    // D layout: lane holds col=lr, row=4*lg+reg
    #pragma unroll
    for (int i = 0; i < 4; ++i) {
        #pragma unroll
        for (int j = 0; j < 4; ++j) {
            int col = n0 + wc * 64 + j * 16 + lr;
            float badd = (BF16OUT && bias) ? bias[col] : 0.f;
            #pragma unroll
            for (int reg = 0; reg < 4; ++reg) {
                int row = m0 + wr * 64 + i * 16 + 4 * lg + reg;
                float v = acc[i][j][reg] + badd;
                if (BF16OUT)
                    ((ushort*)Cc)[(size_t)row * N + col] = f2bf(v);
                else
                    ((float*)Cc)[(size_t)row * N + col] = v;
            }
        }
    }
}

// ---------------- Poincare epilogue: P fp32 -> ball point, bf16 out ----------
__global__ __launch_bounds__(256) void poincare_epilogue(const float* __restrict__ x,
                                                         const float* __restrict__ P,
                                                         const float* __restrict__ zn,
                                                         const float* __restrict__ ch,
                                                         const float* __restrict__ sh,
                                                         ushort* __restrict__ outb,
                                                         float oscale) {
    __shared__ float sbuf[4];
    int n = blockIdx.x;
    const float* xr = x + (size_t)n * D_MODEL;
    float s = 0.f;
    #pragma unroll
    for (int i = 0; i < 4; ++i) {
        float xv = xr[threadIdx.x + 256 * i];
        s += xv * xv;
    }
    float xn2 = block_reduce_sum(s, sbuf);
    float lam = 2.f / (1.f - xn2);
    float w[4];
    float wn2 = 0.f;
    #pragma unroll
    for (int i = 0; i < 4; ++i) {
        int o = threadIdx.x + 256 * i;
        float zno = zn[o];
        float inner = P[(size_t)n * D_MODEL + o] / zno;
        float t = lam * inner * ch[o] - (lam - 1.f) * sh[o];
        float v = 2.f * zno * asinhf(t);
        w[i] = sinhf(v);
        wn2 += w[i] * w[i];
    }
    wn2 = block_reduce_sum(wn2, sbuf);
    float invd = 1.f / (1.f + sqrtf(1.f + wn2));
    #pragma unroll
    for (int i = 0; i < 4; ++i) {
        int o = threadIdx.x + 256 * i;
        outb[(size_t)n * D_MODEL + o] = f2bf(w[i] * invd * oscale);
    }
}

// ---------------- MFMA attention (unchanged, verified) -----------------------
__global__ __launch_bounds__(256) void attn_mfma(const ushort* __restrict__ Qb,
                                                 const ushort* __restrict__ Kb,
                                                 const ushort* __restrict__ Vb,
                                                 float* __restrict__ Out) {
    __shared__ ushort Klds[64 * 64];      // [key][dk], byte ^= (key&7)<<4
    __shared__ ushort Vlds[64 * 64];      // [dk][key], byte ^= (((dk>>3)^dk)&7)<<4
    __shared__ ushort Plds[4][16 * 64];   // per-wave [r][key], byte ^= (r&7)<<4

    int tid = threadIdx.x;
    int w = tid >> 6, l = tid & 63;
    int lr = l & 15, lg = l >> 4;
    int h = blockIdx.y, b = blockIdx.z;
    size_t headoff = (size_t)b * SEQ * D_MODEL + h * DKH;

    const ushort* qp = Qb + headoff + (size_t)(blockIdx.x * 64 + w * 16 + lr) * D_MODEL;
    v8bf qa0 = ld_bf16x8(qp + lg * 8);
    v8bf qa1 = ld_bf16x8(qp + 32 + lg * 8);

    v4f o[4];
    float den[4];
    #pragma unroll
    for (int i = 0; i < 4; ++i) { o[i] = (v4f){0.f, 0.f, 0.f, 0.f}; den[i] = 0.f; }

    for (int kv0 = 0; kv0 < SEQ; kv0 += 64) {
        #pragma unroll
        for (int i = 0; i < 2; ++i) {
            int idx = tid + 256 * i;
            int key = idx >> 3, c8 = idx & 7;
            uint4 kv = *(const uint4*)(Kb + headoff + (size_t)(kv0 + key) * D_MODEL + c8 * 8);
            *(uint4*)((char*)Klds + key * 128 + ((c8 * 16) ^ ((key & 7) << 4))) = kv;
            uint4 vv = *(const uint4*)(Vb + headoff + (size_t)(kv0 + key) * D_MODEL + c8 * 8);
            uint vals[4] = {vv.x, vv.y, vv.z, vv.w};
            #pragma unroll
            for (int j = 0; j < 8; ++j) {
                int dk = c8 * 8 + j;
                ushort u = (ushort)(vals[j >> 1] >> ((j & 1) * 16));
                int s = ((dk >> 3) ^ dk) & 7;
                *(ushort*)((char*)Vlds + dk * 128 + ((key * 2) ^ (s << 4))) = u;
            }
        }
        __syncthreads();

        v4f sc[4];
        #pragma unroll
        for (int i = 0; i < 4; ++i) sc[i] = (v4f){0.f, 0.f, 0.f, 0.f};
        #pragma unroll
        for (int f = 0; f < 2; ++f) {
            v8bf qa = f ? qa1 : qa0;
            #pragma unroll
            for (int sub = 0; sub < 4; ++sub) {
                int key = sub * 16 + lr;
                v8bf kb = *(const v8bf*)((char*)Klds + key * 128 +
                                         ((f * 64 + lg * 16) ^ ((key & 7) << 4)));
                sc[sub] = __builtin_amdgcn_mfma_f32_16x16x32_bf16(qa, kb, sc[sub], 0, 0, 0);
            }
        }

        #pragma unroll
        for (int sub = 0; sub < 4; ++sub) {
            #pragma unroll
            for (int reg = 0; reg < 4; ++reg) {
                float p = __expf(sc[sub][reg]);
                den[reg] += p;
                int r = lg * 4 + reg;
                int key = sub * 16 + lr;
                *(ushort*)((char*)&Plds[w][0] + r * 128 + ((key * 2) ^ ((r & 7) << 4))) = f2bf(p);
            }
        }

        #pragma unroll
        for (int f = 0; f < 2; ++f) {
            v8bf pa = *(const v8bf*)((char*)&Plds[w][0] + lr * 128 +
                                     ((f * 64 + lg * 16) ^ ((lr & 7) << 4)));
            #pragma unroll
            for (int sub = 0; sub < 4; ++sub) {
                int dk = sub * 16 + lr;
                int s = ((dk >> 3) ^ dk) & 7;
                v8bf vbf = *(const v8bf*)((char*)Vlds + dk * 128 +
                                          ((f * 64 + lg * 16) ^ (s << 4)));
                o[sub] = __builtin_amdgcn_mfma_f32_16x16x32_bf16(pa, vbf, o[sub], 0, 0, 0);
            }
        }
        __syncthreads();
    }

    #pragma unroll
    for (int m = 1; m < 16; m <<= 1) {
        #pragma unroll
        for (int reg = 0; reg < 4; ++reg)
            den[reg] += __shfl_xor(den[reg], m, 64);
    }
    size_t obase = (size_t)b * SEQ * D_MODEL +
                   (size_t)(blockIdx.x * 64 + w * 16 + lg * 4) * D_MODEL + h * DKH;
    #pragma unroll
    for (int reg = 0; reg < 4; ++reg) {
        float inv = 1.f / den[reg];
        #pragma unroll
        for (int sub = 0; sub < 4; ++sub)
            Out[obase + (size_t)reg * D_MODEL + sub * 16 + lr] = o[sub][reg] * inv;
    }
}

extern "C" void kernel_launch(void* const* d_in, const int* in_sizes, int n_in,
                              void* d_out, int out_size, void* d_ws, size_t ws_size,
                              hipStream_t stream) {
    const float* x   = (const float*)d_in[0];
    const float* z_q = (const float*)d_in[1];
    const float* b_q = (const float*)d_in[2];
    const float* z_k = (const float*)d_in[3];
    const float* b_k = (const float*)d_in[4];
    const float* w_v = (const float*)d_in[5];
    const float* b_v = (const float*)d_in[6];
    float* out = (float*)d_out;

    // ws layout (peak ~86MB):
    //   Pf fp32 32MB  (Vb bf16 16MB aliases its first half; Pf dead before V GEMM)
    //   xb 16MB | zqT 2MB | zkT 2MB | wvb 2MB | Qb 16MB | Kb 16MB | aux
    float*  Pf  = (float*)d_ws;
    ushort* Vb  = (ushort*)Pf;
    ushort* xb  = (ushort*)(Pf + NELEM);
    ushort* zqT = xb + NELEM;
    ushort* zkT = zqT + (size_t)D_MODEL * D_MODEL;
    ushort* wvb = zkT + (size_t)D_MODEL * D_MODEL;
    ushort* Qb  = wvb + (size_t)D_MODEL * D_MODEL;
    ushort* Kb  = Qb + NELEM;
    float*  aux = (float*)(Kb + NELEM);
    float* znq = aux;        float* chq = aux + 1024; float* shq = aux + 2048;
    float* znk = aux + 3072; float* chk = aux + 4096; float* shk = aux + 5120;

    prep_kernel<<<dim3(1024), 256, 0, stream>>>(z_q, b_q, znq, chq, shq);
    prep_kernel<<<dim3(1024), 256, 0, stream>>>(z_k, b_k, znk, chk, shk);

    cast_bf16<<<dim3(NELEM / 8 / 256), 256, 0, stream>>>(x, xb);
    cast_transpose_bf16<<<dim3(16, 16), 256, 0, stream>>>(z_q, zqT);
    cast_transpose_bf16<<<dim3(16, 16), 256, 0, stream>>>(z_k, zkT);
    cast_bf16<<<dim3(D_MODEL * D_MODEL / 8 / 256), 256, 0, stream>>>(w_v, wvb);

    // Q chain
    gemm_bf16<0><<<dim3(8, 64), 256, 0, stream>>>(xb, zqT, nullptr, Pf);
    poincare_epilogue<<<dim3(NTOK), 256, 0, stream>>>(x, Pf, znq, chq, shq, Qb, 0.125f);
    // K chain (reuses Pf)
    gemm_bf16<0><<<dim3(8, 64), 256, 0, stream>>>(xb, zkT, nullptr, Pf);
    poincare_epilogue<<<dim3(NTOK), 256, 0, stream>>>(x, Pf, znk, chk, shk, Kb, 1.0f);
    // V chain: bf16 out with bias (Vb aliases Pf region; Pf no longer read)
    gemm_bf16<1><<<dim3(8, 64), 256, 0, stream>>>(xb, wvb, b_v, Vb);

    attn_mfma<<<dim3(SEQ / 64, NHEADS, BATCH), 256, 0, stream>>>(Qb, Kb, Vb, out);
}

// Round 4
// 374.650 us; speedup vs baseline: 8.1132x; 1.1392x over previous
//
#include <hip/hip_runtime.h>
#include <hip/hip_bf16.h>
#include <math.h>

#define D_MODEL 1024
#define NHEADS  16
#define DKH     64
#define BATCH   4
#define SEQ     2048
#define NTOK    (BATCH * SEQ)   // 8192
#define NELEM   ((size_t)NTOK * D_MODEL)  // 8388608

typedef __bf16 v8bf __attribute__((ext_vector_type(8)));
typedef float  v4f  __attribute__((ext_vector_type(4)));

__device__ __forceinline__ v8bf ld_bf16x8(const ushort* p) {
    union { uint4 u; v8bf b; } cv;
    cv.u = *(const uint4*)p;
    return cv.b;
}
__device__ __forceinline__ ushort f2bf(float f) {
    __hip_bfloat16 h = __float2bfloat16(f);
    return *(ushort*)&h;
}

#define GLOAD_LDS16(gsrc, ldst)                                            \
    __builtin_amdgcn_global_load_lds(                                      \
        (const __attribute__((address_space(1))) void*)(gsrc),             \
        (__attribute__((address_space(3))) void*)(ldst), 16, 0, 0)

// ---------------- block reduce (256 threads = 4 waves) ----------------
__device__ __forceinline__ float block_reduce_sum(float v, float* sbuf) {
    #pragma unroll
    for (int off = 32; off > 0; off >>= 1)
        v += __shfl_xor(v, off, 64);
    int lane = threadIdx.x & 63;
    int wid  = threadIdx.x >> 6;
    if (lane == 0) sbuf[wid] = v;
    __syncthreads();
    float total = sbuf[0] + sbuf[1] + sbuf[2] + sbuf[3];
    __syncthreads();
    return total;
}

// ---------------- prep: column norms of z + cosh/sinh(2r) ----------------
__global__ __launch_bounds__(256) void prep_kernel(const float* __restrict__ z,
                                                   const float* __restrict__ r,
                                                   float* __restrict__ zn,
                                                   float* __restrict__ ch,
                                                   float* __restrict__ sh) {
    __shared__ float sbuf[4];
    int m = blockIdx.x;
    float s = 0.f;
    for (int k = threadIdx.x; k < D_MODEL; k += 256) {
        float zv = z[k * D_MODEL + m];
        s += zv * zv;
    }
    float tot = block_reduce_sum(s, sbuf);
    if (threadIdx.x == 0) {
        float n = fmaxf(sqrtf(tot), 1e-15f);
        zn[m] = n;
        float tc = 2.f * r[m];   // c_sqrt = 1
        ch[m] = coshf(tc);
        sh[m] = sinhf(tc);
    }
}

// ---------------- casts ----------------
__global__ __launch_bounds__(256) void cast_bf16(const float* __restrict__ in,
                                                 ushort* __restrict__ out) {
    size_t i = ((size_t)blockIdx.x * 256 + threadIdx.x) * 8;
    float4 a = *(const float4*)(in + i);
    float4 b = *(const float4*)(in + i + 4);
    ushort u[8] = {f2bf(a.x), f2bf(a.y), f2bf(a.z), f2bf(a.w),
                   f2bf(b.x), f2bf(b.y), f2bf(b.z), f2bf(b.w)};
    *(uint4*)(out + i) = *(uint4*)u;
}

// zT[m][k] = z[k][m], 1024x1024, fp32 -> bf16
__global__ __launch_bounds__(256) void cast_transpose_bf16(const float* __restrict__ z,
                                                           ushort* __restrict__ zT) {
    __shared__ float tile[64][65];
    int t = threadIdx.x;
    int k0 = blockIdx.y * 64, m0 = blockIdx.x * 64;
    #pragma unroll
    for (int i = 0; i < 4; ++i) {
        int r = (t >> 4) + 16 * i;
        int c = (t & 15) * 4;
        float4 v = *(const float4*)&z[(size_t)(k0 + r) * D_MODEL + m0 + c];
        tile[r][c + 0] = v.x; tile[r][c + 1] = v.y;
        tile[r][c + 2] = v.z; tile[r][c + 3] = v.w;
    }
    __syncthreads();
    #pragma unroll
    for (int i = 0; i < 2; ++i) {
        int idx = t + 256 * i;
        int r = idx >> 3;        // m-local
        int c8 = idx & 7;        // k-chunk
        ushort u[8];
        #pragma unroll
        for (int j = 0; j < 8; ++j)
            u[j] = f2bf(tile[c8 * 8 + j][r]);
        *(uint4*)&zT[(size_t)(m0 + r) * D_MODEL + k0 + c8 * 8] = *(uint4*)u;
    }
}

// ---------------- bf16 MFMA GEMM (m97 structure, unchanged) ------------------
template<int BF16OUT>
__global__ __launch_bounds__(256) void gemm_bf16(const ushort* __restrict__ A,
                                                 const ushort* __restrict__ Bt,
                                                 const float* __restrict__ bias,
                                                 void* __restrict__ Cc) {
    const int K = 1024, N = 1024;
    __shared__ ushort As[128][64];
    __shared__ ushort Bs[128][64];
    int tid = threadIdx.x;
    int w = tid >> 6, l = tid & 63;
    int lr = l & 15, lg = l >> 4;
    int wr = w >> 1, wc = w & 1;
    int m0 = blockIdx.y * 128;
    int n0 = blockIdx.x * 128;

    v4f acc[4][4];
    #pragma unroll
    for (int i = 0; i < 4; ++i)
        #pragma unroll
        for (int j = 0; j < 4; ++j)
            acc[i][j] = (v4f){0.f, 0.f, 0.f, 0.f};

    int srow = w * 32 + (l >> 3);
    int scol = (l & 7) * 8;

    for (int k0 = 0; k0 < K; k0 += 64) {
        #pragma unroll
        for (int j = 0; j < 4; ++j) {
            GLOAD_LDS16(A  + (size_t)(m0 + srow + j * 8) * K + k0 + scol,
                        &As[w * 32 + j * 8][0]);
            GLOAD_LDS16(Bt + (size_t)(n0 + srow + j * 8) * K + k0 + scol,
                        &Bs[w * 32 + j * 8][0]);
        }
        __syncthreads();
        #pragma unroll
        for (int kk = 0; kk < 2; ++kk) {
            v8bf av[4], bv[4];
            #pragma unroll
            for (int i = 0; i < 4; ++i)
                av[i] = *(const v8bf*)&As[wr * 64 + i * 16 + lr][kk * 32 + lg * 8];
            #pragma unroll
            for (int j = 0; j < 4; ++j)
                bv[j] = *(const v8bf*)&Bs[wc * 64 + j * 16 + lr][kk * 32 + lg * 8];
            #pragma unroll
            for (int i = 0; i < 4; ++i)
                #pragma unroll
                for (int j = 0; j < 4; ++j)
                    acc[i][j] = __builtin_amdgcn_mfma_f32_16x16x32_bf16(av[i], bv[j], acc[i][j], 0, 0, 0);
        }
        __syncthreads();
    }

    #pragma unroll
    for (int i = 0; i < 4; ++i) {
        #pragma unroll
        for (int j = 0; j < 4; ++j) {
            int col = n0 + wc * 64 + j * 16 + lr;
            float badd = (BF16OUT && bias) ? bias[col] : 0.f;
            #pragma unroll
            for (int reg = 0; reg < 4; ++reg) {
                int row = m0 + wr * 64 + i * 16 + 4 * lg + reg;
                float v = acc[i][j][reg] + badd;
                if (BF16OUT)
                    ((ushort*)Cc)[(size_t)row * N + col] = f2bf(v);
                else
                    ((float*)Cc)[(size_t)row * N + col] = v;
            }
        }
    }
}

// ---------------- V transpose: Vb[token][1024] -> VT[b,h,dk,s] ---------------
__global__ __launch_bounds__(256) void transpose_v(const ushort* __restrict__ Vb,
                                                   ushort* __restrict__ VT) {
    __shared__ ushort t[64][72];   // 72 pad: 16B-aligned rows, ~2-way banks
    int tid = threadIdx.x;
    int st = blockIdx.x;           // token tile 0..127
    int h  = blockIdx.y;
    size_t tok0 = (size_t)st * 64;
    int b  = (int)(tok0 >> 11);
    int s0 = (int)(tok0 & 2047);
    #pragma unroll
    for (int i = 0; i < 2; ++i) {
        int idx = tid + 256 * i;
        int r = idx >> 3, c8 = idx & 7;
        uint4 v = *(const uint4*)&Vb[(tok0 + r) * D_MODEL + h * DKH + c8 * 8];
        *(uint4*)&t[r][c8 * 8] = v;
    }
    __syncthreads();
    #pragma unroll
    for (int i = 0; i < 2; ++i) {
        int idx = tid + 256 * i;
        int dk = idx >> 3;
        int s8 = (idx & 7) * 8;
        ushort u[8];
        #pragma unroll
        for (int j = 0; j < 8; ++j)
            u[j] = t[s8 + j][dk];
        *(uint4*)&VT[((size_t)(b * NHEADS + h) * DKH + dk) * SEQ + s0 + s8] = *(uint4*)u;
    }
}

// ---------------- Poincare epilogue: P fp32 -> ball point, bf16 out ----------
__global__ __launch_bounds__(256) void poincare_epilogue(const float* __restrict__ x,
                                                         const float* __restrict__ P,
                                                         const float* __restrict__ zn,
                                                         const float* __restrict__ ch,
                                                         const float* __restrict__ sh,
                                                         ushort* __restrict__ outb,
                                                         float oscale) {
    __shared__ float sbuf[4];
    int n = blockIdx.x;
    const float* xr = x + (size_t)n * D_MODEL;
    float s = 0.f;
    #pragma unroll
    for (int i = 0; i < 4; ++i) {
        float xv = xr[threadIdx.x + 256 * i];
        s += xv * xv;
    }
    float xn2 = block_reduce_sum(s, sbuf);
    float lam = 2.f / (1.f - xn2);
    float w[4];
    float wn2 = 0.f;
    #pragma unroll
    for (int i = 0; i < 4; ++i) {
        int o = threadIdx.x + 256 * i;
        float zno = zn[o];
        float inner = P[(size_t)n * D_MODEL + o] / zno;
        float t = lam * inner * ch[o] - (lam - 1.f) * sh[o];
        float v = 2.f * zno * asinhf(t);
        w[i] = sinhf(v);
        wn2 += w[i] * w[i];
    }
    wn2 = block_reduce_sum(wn2, sbuf);
    float invd = 1.f / (1.f + sqrtf(1.f + wn2));
    #pragma unroll
    for (int i = 0; i < 4; ++i) {
        int o = threadIdx.x + 256 * i;
        outb[(size_t)n * D_MODEL + o] = f2bf(w[i] * invd * oscale);
    }
}

// ---------------- MFMA attention v2 ------------------------------------------
// Swapped QK^T (mfma(K,Q) -> S^T), DMA-staged K and pre-transposed V with
// XOR-swizzled source/read, packed u32 P writes, 2-phase double buffer.
// Scores bounded: |q.k|/8 <= 1/8 (Poincare ball) => plain exp, fp32 den/O.
__global__ __launch_bounds__(256) void attn_mfma(const ushort* __restrict__ Qb,
                                                 const ushort* __restrict__ Kb,
                                                 const ushort* __restrict__ VT,
                                                 float* __restrict__ Out) {
    __shared__ ushort Klds[2][64 * 64];   // [key][dk], chunk pos = c8 ^ (key&7)
    __shared__ ushort Vlds[2][64 * 64];   // [dk][key], chunk pos = c8 ^ (dk&7)
    __shared__ ushort Plds[4][16 * 64];   // per-wave [q][key], byte ^= (q&7)<<4

    int tid = threadIdx.x;
    int w = tid >> 6, l = tid & 63;
    int lr = l & 15, lg = l >> 4;

    // XCD swizzle: flat' = (g&7) + 8*(x + 32*(g>>3)); decode back
    int flat = blockIdx.x;
    int low3 = flat & 7;
    int rest = flat >> 3;
    int qx   = rest & 31;          // q-tile 0..31
    int g    = ((rest >> 5) << 3) | low3;   // (b,h) group 0..63
    int h = g & 15, b = g >> 4;

    const ushort* Kh = Kb + (size_t)b * SEQ * D_MODEL + h * DKH;
    const ushort* Vh = VT + (size_t)(b * NHEADS + h) * DKH * SEQ;

    // Q fragments (scale 1/8 folded at epilogue); lane holds Q[q=lr][k]
    const ushort* qp = Qb + (size_t)b * SEQ * D_MODEL + h * DKH
                     + (size_t)(qx * 64 + w * 16 + lr) * D_MODEL;
    v8bf qa0 = ld_bf16x8(qp + lg * 8);
    v8bf qa1 = ld_bf16x8(qp + 32 + lg * 8);

    // staging constants: 2 DMA issues per array per thread, pre-swizzled source
    int slot0 = (w * 2) * 64 + l;
    int slot1 = (w * 2 + 1) * 64 + l;
    int row0 = slot0 >> 3, c80 = (slot0 & 7) ^ (row0 & 7);
    int row1 = slot1 >> 3, c81 = (slot1 & 7) ^ (row1 & 7);
    const ushort* kg0 = Kh + (size_t)row0 * D_MODEL + c80 * 8;
    const ushort* kg1 = Kh + (size_t)row1 * D_MODEL + c81 * 8;
    const ushort* vg0 = Vh + (size_t)row0 * SEQ + c80 * 8;
    const ushort* vg1 = Vh + (size_t)row1 * SEQ + c81 * 8;

#define STAGE_KV(buf, kv)  do {                                              \
        GLOAD_LDS16(kg0 + (size_t)(kv) * D_MODEL, &Klds[buf][(w * 2 + 0) * 512]); \
        GLOAD_LDS16(kg1 + (size_t)(kv) * D_MODEL, &Klds[buf][(w * 2 + 1) * 512]); \
        GLOAD_LDS16(vg0 + (kv), &Vlds[buf][(w * 2 + 0) * 512]);               \
        GLOAD_LDS16(vg1 + (kv), &Vlds[buf][(w * 2 + 1) * 512]);               \
    } while (0)

    v4f o[4];
    #pragma unroll
    for (int i = 0; i < 4; ++i) o[i] = (v4f){0.f, 0.f, 0.f, 0.f};
    float den = 0.f;
    char* Pw = (char*)&Plds[w][0];
    int swzp = (lr & 7) << 4;

    STAGE_KV(0, 0);
    asm volatile("s_waitcnt vmcnt(0)" ::: "memory");
    __syncthreads();

    int cur = 0;
    for (int kv0 = 0; kv0 < SEQ; kv0 += 64) {
        if (kv0 + 64 < SEQ) STAGE_KV(cur ^ 1, kv0 + 64);
        const char* Kc = (const char*)&Klds[cur][0];
        const char* Vc = (const char*)&Vlds[cur][0];

        // ---- QK^T swapped: D = S^T[key][q]; lane: q=lr, key=sub*16+4lg+reg --
        v4f sc[4];
        #pragma unroll
        for (int i = 0; i < 4; ++i) sc[i] = (v4f){0.f, 0.f, 0.f, 0.f};
        #pragma unroll
        for (int f = 0; f < 2; ++f) {
            v8bf qa = f ? qa1 : qa0;
            #pragma unroll
            for (int sub = 0; sub < 4; ++sub) {
                int key = sub * 16 + lr;
                v8bf kb = *(const v8bf*)(Kc + key * 128 +
                                         ((f * 64 + lg * 16) ^ ((key & 7) << 4)));
                sc[sub] = __builtin_amdgcn_mfma_f32_16x16x32_bf16(kb, qa, sc[sub], 0, 0, 0);
            }
        }

        // ---- exp + den + packed P write (u32, 2-way banks = free) ----
        #pragma unroll
        for (int sub = 0; sub < 4; ++sub) {
            float p0 = __expf(sc[sub][0]), p1 = __expf(sc[sub][1]);
            float p2 = __expf(sc[sub][2]), p3 = __expf(sc[sub][3]);
            den += (p0 + p1) + (p2 + p3);
            uint u0 = (uint)f2bf(p0) | ((uint)f2bf(p1) << 16);
            uint u1 = (uint)f2bf(p2) | ((uint)f2bf(p3) << 16);
            int base = sub * 32 + lg * 8;   // byte offset of key pair (q row = lr)
            *(uint*)(Pw + lr * 128 + ((base + 0) ^ swzp)) = u0;
            *(uint*)(Pw + lr * 128 + ((base + 4) ^ swzp)) = u1;
        }

        // ---- PV: O[q][dk] += P[q][k] V[k][dk] ----
        #pragma unroll
        for (int f = 0; f < 2; ++f) {
            v8bf pa = *(const v8bf*)(Pw + lr * 128 + ((f * 64 + lg * 16) ^ swzp));
            #pragma unroll
            for (int sub = 0; sub < 4; ++sub) {
                int dk = sub * 16 + lr;
                v8bf vb = *(const v8bf*)(Vc + dk * 128 +
                                         ((f * 64 + lg * 16) ^ ((dk & 7) << 4)));
                o[sub] = __builtin_amdgcn_mfma_f32_16x16x32_bf16(pa, vb, o[sub], 0, 0, 0);
            }
        }

        asm volatile("s_waitcnt vmcnt(0)" ::: "memory");
        __syncthreads();
        cur ^= 1;
    }

    // den: lane holds partial for q=lr; sum the 4 lane-groups
    den += __shfl_xor(den, 16, 64);
    den += __shfl_xor(den, 32, 64);

    size_t obase = (size_t)b * SEQ * D_MODEL +
                   (size_t)(qx * 64 + w * 16 + lg * 4) * D_MODEL + h * DKH;
    #pragma unroll
    for (int reg = 0; reg < 4; ++reg) {
        float inv = 1.f / __shfl(den, 4 * lg + reg, 64);
        #pragma unroll
        for (int sub = 0; sub < 4; ++sub)
            Out[obase + (size_t)reg * D_MODEL + sub * 16 + lr] = o[sub][reg] * inv;
    }
#undef STAGE_KV
}

extern "C" void kernel_launch(void* const* d_in, const int* in_sizes, int n_in,
                              void* d_out, int out_size, void* d_ws, size_t ws_size,
                              hipStream_t stream) {
    const float* x   = (const float*)d_in[0];
    const float* z_q = (const float*)d_in[1];
    const float* b_q = (const float*)d_in[2];
    const float* z_k = (const float*)d_in[3];
    const float* b_k = (const float*)d_in[4];
    const float* w_v = (const float*)d_in[5];
    const float* b_v = (const float*)d_in[6];
    float* out = (float*)d_out;

    // ws layout (peak ~86MB): Pf fp32 32MB (after K-epilogue dead, reused:
    //   Vb bf16 16MB = first half, VT bf16 16MB = second half)
    //   xb 16MB | zqT 2MB | zkT 2MB | wvb 2MB | Qb 16MB | Kb 16MB | aux
    float*  Pf  = (float*)d_ws;
    ushort* Vb  = (ushort*)Pf;                       // aliases Pf[0 .. NELEM/2)
    ushort* VT  = (ushort*)(Pf + NELEM / 2);         // aliases Pf[NELEM/2 .. NELEM)
    ushort* xb  = (ushort*)(Pf + NELEM);
    ushort* zqT = xb + NELEM;
    ushort* zkT = zqT + (size_t)D_MODEL * D_MODEL;
    ushort* wvb = zkT + (size_t)D_MODEL * D_MODEL;
    ushort* Qb  = wvb + (size_t)D_MODEL * D_MODEL;
    ushort* Kb  = Qb + NELEM;
    float*  aux = (float*)(Kb + NELEM);
    float* znq = aux;        float* chq = aux + 1024; float* shq = aux + 2048;
    float* znk = aux + 3072; float* chk = aux + 4096; float* shk = aux + 5120;

    prep_kernel<<<dim3(1024), 256, 0, stream>>>(z_q, b_q, znq, chq, shq);
    prep_kernel<<<dim3(1024), 256, 0, stream>>>(z_k, b_k, znk, chk, shk);

    cast_bf16<<<dim3(NELEM / 8 / 256), 256, 0, stream>>>(x, xb);
    cast_transpose_bf16<<<dim3(16, 16), 256, 0, stream>>>(z_q, zqT);
    cast_transpose_bf16<<<dim3(16, 16), 256, 0, stream>>>(z_k, zkT);
    cast_bf16<<<dim3(D_MODEL * D_MODEL / 8 / 256), 256, 0, stream>>>(w_v, wvb);

    // Q chain (scale 1/8 folded into bf16 Q)
    gemm_bf16<0><<<dim3(8, 64), 256, 0, stream>>>(xb, zqT, nullptr, Pf);
    poincare_epilogue<<<dim3(NTOK), 256, 0, stream>>>(x, Pf, znq, chq, shq, Qb, 0.125f);
    // K chain (reuses Pf)
    gemm_bf16<0><<<dim3(8, 64), 256, 0, stream>>>(xb, zkT, nullptr, Pf);
    poincare_epilogue<<<dim3(NTOK), 256, 0, stream>>>(x, Pf, znk, chk, shk, Kb, 1.0f);
    // V chain: bf16 out with bias (Vb aliases Pf's first half; Pf dead now)
    gemm_bf16<1><<<dim3(8, 64), 256, 0, stream>>>(xb, wvb, b_v, Vb);
    // V -> per-head transposed layout for DMA-staged attention B-operand
    transpose_v<<<dim3(128, 16), 256, 0, stream>>>(Vb, VT);

    attn_mfma<<<dim3(2048), 256, 0, stream>>>(Qb, Kb, VT, out);
}

// Round 5
// 372.217 us; speedup vs baseline: 8.1663x; 1.0065x over previous
//
#include <hip/hip_runtime.h>
#include <hip/hip_bf16.h>
#include <math.h>

#define D_MODEL 1024
#define NHEADS  16
#define DKH     64
#define BATCH   4
#define SEQ     2048
#define NTOK    (BATCH * SEQ)   // 8192
#define NELEM   ((size_t)NTOK * D_MODEL)  // 8388608

typedef __bf16 v8bf __attribute__((ext_vector_type(8)));
typedef float  v4f  __attribute__((ext_vector_type(4)));

__device__ __forceinline__ v8bf ld_bf16x8(const ushort* p) {
    union { uint4 u; v8bf b; } cv;
    cv.u = *(const uint4*)p;
    return cv.b;
}
__device__ __forceinline__ ushort f2bf(float f) {
    __hip_bfloat16 h = __float2bfloat16(f);
    return *(ushort*)&h;
}

#define GLOAD_LDS16(gsrc, ldst)                                            \
    __builtin_amdgcn_global_load_lds(                                      \
        (const __attribute__((address_space(1))) void*)(gsrc),             \
        (__attribute__((address_space(3))) void*)(ldst), 16, 0, 0)

// ---------------- block reduce (256 threads = 4 waves) ----------------
__device__ __forceinline__ float block_reduce_sum(float v, float* sbuf) {
    #pragma unroll
    for (int off = 32; off > 0; off >>= 1)
        v += __shfl_xor(v, off, 64);
    int lane = threadIdx.x & 63;
    int wid  = threadIdx.x >> 6;
    if (lane == 0) sbuf[wid] = v;
    __syncthreads();
    float total = sbuf[0] + sbuf[1] + sbuf[2] + sbuf[3];
    __syncthreads();
    return total;
}

// ---------------- prep: column norms of z + cosh/sinh(2r) ----------------
__global__ __launch_bounds__(256) void prep_kernel(const float* __restrict__ z,
                                                   const float* __restrict__ r,
                                                   float* __restrict__ zn,
                                                   float* __restrict__ ch,
                                                   float* __restrict__ sh) {
    __shared__ float sbuf[4];
    int m = blockIdx.x;
    float s = 0.f;
    for (int k = threadIdx.x; k < D_MODEL; k += 256) {
        float zv = z[k * D_MODEL + m];
        s += zv * zv;
    }
    float tot = block_reduce_sum(s, sbuf);
    if (threadIdx.x == 0) {
        float n = fmaxf(sqrtf(tot), 1e-15f);
        zn[m] = n;
        float tc = 2.f * r[m];   // c_sqrt = 1
        ch[m] = coshf(tc);
        sh[m] = sinhf(tc);
    }
}

// ---------------- x -> bf16 cast + per-row lam = 2/(1-|x|^2) -----------------
__global__ __launch_bounds__(256) void cast_x_lam(const float* __restrict__ x,
                                                  ushort* __restrict__ xb,
                                                  float* __restrict__ lam) {
    __shared__ float sbuf[4];
    int n = blockIdx.x;
    const float* xr = x + (size_t)n * D_MODEL;
    float4 v = *(const float4*)&xr[threadIdx.x * 4];
    float s = v.x * v.x + v.y * v.y + v.z * v.z + v.w * v.w;
    float xn2 = block_reduce_sum(s, sbuf);
    if (threadIdx.x == 0) lam[n] = 2.f / (1.f - xn2);
    ushort u[4] = {f2bf(v.x), f2bf(v.y), f2bf(v.z), f2bf(v.w)};
    *(uint2*)&xb[(size_t)n * D_MODEL + threadIdx.x * 4] = *(uint2*)u;
}

// ---------------- generic fp32 -> bf16 cast (weights) ----------------
__global__ __launch_bounds__(256) void cast_bf16(const float* __restrict__ in,
                                                 ushort* __restrict__ out) {
    size_t i = ((size_t)blockIdx.x * 256 + threadIdx.x) * 8;
    float4 a = *(const float4*)(in + i);
    float4 b = *(const float4*)(in + i + 4);
    ushort u[8] = {f2bf(a.x), f2bf(a.y), f2bf(a.z), f2bf(a.w),
                   f2bf(b.x), f2bf(b.y), f2bf(b.z), f2bf(b.w)};
    *(uint4*)(out + i) = *(uint4*)u;
}

// zT[m][k] = z[k][m], 1024x1024, fp32 -> bf16
__global__ __launch_bounds__(256) void cast_transpose_bf16(const float* __restrict__ z,
                                                           ushort* __restrict__ zT) {
    __shared__ float tile[64][65];
    int t = threadIdx.x;
    int k0 = blockIdx.y * 64, m0 = blockIdx.x * 64;
    #pragma unroll
    for (int i = 0; i < 4; ++i) {
        int r = (t >> 4) + 16 * i;
        int c = (t & 15) * 4;
        float4 v = *(const float4*)&z[(size_t)(k0 + r) * D_MODEL + m0 + c];
        tile[r][c + 0] = v.x; tile[r][c + 1] = v.y;
        tile[r][c + 2] = v.z; tile[r][c + 3] = v.w;
    }
    __syncthreads();
    #pragma unroll
    for (int i = 0; i < 2; ++i) {
        int idx = t + 256 * i;
        int r = idx >> 3;        // m-local
        int c8 = idx & 7;        // k-chunk
        ushort u[8];
        #pragma unroll
        for (int j = 0; j < 8; ++j)
            u[j] = f2bf(tile[c8 * 8 + j][r]);
        *(uint4*)&zT[(size_t)(m0 + r) * D_MODEL + k0 + c8 * 8] = *(uint4*)u;
    }
}

// ---------------- bf16 MFMA GEMM (m97 structure) -----------------------------
// MODE 0: fp32 C row-major. MODE 2: bf16 out transposed per-head VT[b,h,dk,s],
// with bias (V chain; transpose folded into the C-write).
template<int MODE>
__global__ __launch_bounds__(256) void gemm_bf16(const ushort* __restrict__ A,
                                                 const ushort* __restrict__ Bt,
                                                 const float* __restrict__ bias,
                                                 void* __restrict__ Cc) {
    const int K = 1024, N = 1024;
    __shared__ ushort As[128][64];
    __shared__ ushort Bs[128][64];
    int tid = threadIdx.x;
    int w = tid >> 6, l = tid & 63;
    int lr = l & 15, lg = l >> 4;
    int wr = w >> 1, wc = w & 1;
    int m0 = blockIdx.y * 128;
    int n0 = blockIdx.x * 128;

    v4f acc[4][4];
    #pragma unroll
    for (int i = 0; i < 4; ++i)
        #pragma unroll
        for (int j = 0; j < 4; ++j)
            acc[i][j] = (v4f){0.f, 0.f, 0.f, 0.f};

    int srow = w * 32 + (l >> 3);
    int scol = (l & 7) * 8;

    for (int k0 = 0; k0 < K; k0 += 64) {
        #pragma unroll
        for (int j = 0; j < 4; ++j) {
            GLOAD_LDS16(A  + (size_t)(m0 + srow + j * 8) * K + k0 + scol,
                        &As[w * 32 + j * 8][0]);
            GLOAD_LDS16(Bt + (size_t)(n0 + srow + j * 8) * K + k0 + scol,
                        &Bs[w * 32 + j * 8][0]);
        }
        __syncthreads();
        #pragma unroll
        for (int kk = 0; kk < 2; ++kk) {
            v8bf av[4], bv[4];
            #pragma unroll
            for (int i = 0; i < 4; ++i)
                av[i] = *(const v8bf*)&As[wr * 64 + i * 16 + lr][kk * 32 + lg * 8];
            #pragma unroll
            for (int j = 0; j < 4; ++j)
                bv[j] = *(const v8bf*)&Bs[wc * 64 + j * 16 + lr][kk * 32 + lg * 8];
            #pragma unroll
            for (int i = 0; i < 4; ++i)
                #pragma unroll
                for (int j = 0; j < 4; ++j)
                    acc[i][j] = __builtin_amdgcn_mfma_f32_16x16x32_bf16(av[i], bv[j], acc[i][j], 0, 0, 0);
        }
        __syncthreads();
    }

    // D layout: lane holds col=lr, rows 4*lg+reg (reg 0..3 consecutive)
    #pragma unroll
    for (int i = 0; i < 4; ++i) {
        #pragma unroll
        for (int j = 0; j < 4; ++j) {
            int col = n0 + wc * 64 + j * 16 + lr;
            if (MODE == 0) {
                #pragma unroll
                for (int reg = 0; reg < 4; ++reg) {
                    int row = m0 + wr * 64 + i * 16 + 4 * lg + reg;
                    ((float*)Cc)[(size_t)row * N + col] = acc[i][j][reg];
                }
            } else {
                float badd = bias[col];
                int hh = col >> 6, dk = col & 63;
                int row = m0 + wr * 64 + i * 16 + 4 * lg;   // 4 consecutive tokens
                int bb = row >> 11, ss = row & 2047;
                ushort u[4];
                #pragma unroll
                for (int reg = 0; reg < 4; ++reg)
                    u[reg] = f2bf(acc[i][j][reg] + badd);
                *(uint2*)&((ushort*)Cc)[(((size_t)(bb * NHEADS + hh)) * DKH + dk) * SEQ + ss] = *(uint2*)u;
            }
        }
    }
}

// ---------------- Poincare epilogue: P fp32 -> ball point, bf16 out ----------
__global__ __launch_bounds__(256) void poincare_epilogue(const float* __restrict__ P,
                                                         const float* __restrict__ lam_,
                                                         const float* __restrict__ zn,
                                                         const float* __restrict__ ch,
                                                         const float* __restrict__ sh,
                                                         ushort* __restrict__ outb,
                                                         float oscale) {
    __shared__ float sbuf[4];
    int n = blockIdx.x;
    float lam = lam_[n];
    float w[4];
    float wn2 = 0.f;
    #pragma unroll
    for (int i = 0; i < 4; ++i) {
        int o = threadIdx.x + 256 * i;
        float zno = zn[o];
        float inner = P[(size_t)n * D_MODEL + o] / zno;
        float t = lam * inner * ch[o] - (lam - 1.f) * sh[o];
        float v = 2.f * zno * asinhf(t);
        w[i] = sinhf(v);
        wn2 += w[i] * w[i];
    }
    wn2 = block_reduce_sum(wn2, sbuf);
    float invd = 1.f / (1.f + sqrtf(1.f + wn2));
    #pragma unroll
    for (int i = 0; i < 4; ++i) {
        int o = threadIdx.x + 256 * i;
        outb[(size_t)n * D_MODEL + o] = f2bf(w[i] * invd * oscale);
    }
}

// ---------------- MFMA attention v3 ------------------------------------------
// 8 waves / 128 q-rows per block (2x arithmetic intensity on staged K/V).
// Swapped QK^T (mfma(K,Q) -> S^T), DMA staging w/ pre-swizzled source,
// uint2 packed P writes, exp2 with log2e/8 folded into Q, 2-phase dbuf.
// Scores bounded: |q.k|/8 <= 1/8 (Poincare ball) => plain exp, fp32 den/O.
__global__ __launch_bounds__(512) void attn_mfma(const ushort* __restrict__ Qb,
                                                 const ushort* __restrict__ Kb,
                                                 const ushort* __restrict__ VT,
                                                 float* __restrict__ Out) {
    __shared__ ushort Klds[2][64 * 64];   // [key][dk], chunk pos = c8 ^ (key&7)
    __shared__ ushort Vlds[2][64 * 64];   // [dk][key], chunk pos = c8 ^ (dk&7)
    __shared__ ushort Plds[8][16 * 64];   // per-wave [q][key], byte ^= (q&7)<<4

    int tid = threadIdx.x;
    int w = tid >> 6, l = tid & 63;
    int lr = l & 15, lg = l >> 4;

    // XCD swizzle: 1024 blocks; xcd = flat&7 owns 8 (b,h) groups x 16 q-tiles
    int flat = blockIdx.x;
    int low3 = flat & 7;
    int rest = flat >> 3;            // 0..127
    int qx   = rest & 15;            // q-tile 0..15
    int g    = ((rest >> 4) << 3) | low3;   // (b,h) 0..63
    int h = g & 15, b = g >> 4;

    const ushort* Kh = Kb + (size_t)b * SEQ * D_MODEL + h * DKH;
    const ushort* Vh = VT + (size_t)(b * NHEADS + h) * DKH * SEQ;

    // Q fragments (scale log2e/8 folded at epilogue); lane holds Q[q=lr][k]
    const ushort* qp = Qb + (size_t)b * SEQ * D_MODEL + h * DKH
                     + (size_t)(qx * 128 + w * 16 + lr) * D_MODEL;
    v8bf qa0 = ld_bf16x8(qp + lg * 8);
    v8bf qa1 = ld_bf16x8(qp + 32 + lg * 8);

    // staging: 1 K-DMA + 1 V-DMA per thread per tile, pre-swizzled source
    int row = tid >> 3;                       // 0..63
    int c8  = (tid & 7) ^ (row & 7);
    const ushort* kg = Kh + (size_t)row * D_MODEL + c8 * 8;
    const ushort* vg = Vh + (size_t)row * SEQ + c8 * 8;

#define STAGE_KV(buf, kv)  do {                                   \
        GLOAD_LDS16(kg + (size_t)(kv) * D_MODEL, &Klds[buf][tid * 8]); \
        GLOAD_LDS16(vg + (kv), &Vlds[buf][tid * 8]);              \
    } while (0)

    v4f o[4];
    #pragma unroll
    for (int i = 0; i < 4; ++i) o[i] = (v4f){0.f, 0.f, 0.f, 0.f};
    float den = 0.f;
    char* Pw = (char*)&Plds[w][0];
    int swzp = (lr & 7) << 4;

    STAGE_KV(0, 0);
    asm volatile("s_waitcnt vmcnt(0)" ::: "memory");
    __syncthreads();

    int cur = 0;
    for (int kv0 = 0; kv0 < SEQ; kv0 += 64) {
        if (kv0 + 64 < SEQ) STAGE_KV(cur ^ 1, kv0 + 64);
        const char* Kc = (const char*)&Klds[cur][0];
        const char* Vc = (const char*)&Vlds[cur][0];

        // ---- QK^T swapped: D = S^T[key][q]; lane: q=lr, key=sub*16+4lg+reg --
        v4f sc[4];
        #pragma unroll
        for (int i = 0; i < 4; ++i) sc[i] = (v4f){0.f, 0.f, 0.f, 0.f};
        #pragma unroll
        for (int f = 0; f < 2; ++f) {
            v8bf qa = f ? qa1 : qa0;
            #pragma unroll
            for (int sub = 0; sub < 4; ++sub) {
                int key = sub * 16 + lr;
                v8bf kb = *(const v8bf*)(Kc + key * 128 +
                                         ((f * 64 + lg * 16) ^ ((key & 7) << 4)));
                sc[sub] = __builtin_amdgcn_mfma_f32_16x16x32_bf16(kb, qa, sc[sub], 0, 0, 0);
            }
        }

        // ---- exp2 (log2e pre-folded) + den + packed uint2 P write ----
        #pragma unroll
        for (int sub = 0; sub < 4; ++sub) {
            float p0 = exp2f(sc[sub][0]), p1 = exp2f(sc[sub][1]);
            float p2 = exp2f(sc[sub][2]), p3 = exp2f(sc[sub][3]);
            den += (p0 + p1) + (p2 + p3);
            uint2 u;
            u.x = (uint)f2bf(p0) | ((uint)f2bf(p1) << 16);
            u.y = (uint)f2bf(p2) | ((uint)f2bf(p3) << 16);
            int base = sub * 32 + lg * 8;   // 8B-aligned; swzp is 16B-aligned
            *(uint2*)(Pw + lr * 128 + (base ^ swzp)) = u;
        }

        // ---- PV: O[q][dk] += P[q][k] V[k][dk] ----
        #pragma unroll
        for (int f = 0; f < 2; ++f) {
            v8bf pa = *(const v8bf*)(Pw + lr * 128 + ((f * 64 + lg * 16) ^ swzp));
            #pragma unroll
            for (int sub = 0; sub < 4; ++sub) {
                int dk = sub * 16 + lr;
                v8bf vb = *(const v8bf*)(Vc + dk * 128 +
                                         ((f * 64 + lg * 16) ^ ((dk & 7) << 4)));
                o[sub] = __builtin_amdgcn_mfma_f32_16x16x32_bf16(pa, vb, o[sub], 0, 0, 0);
            }
        }

        asm volatile("s_waitcnt vmcnt(0)" ::: "memory");
        __syncthreads();
        cur ^= 1;
    }

    // den: lane holds partial for q=lr; sum the 4 lane-groups
    den += __shfl_xor(den, 16, 64);
    den += __shfl_xor(den, 32, 64);

    size_t obase = (size_t)b * SEQ * D_MODEL +
                   (size_t)(qx * 128 + w * 16 + lg * 4) * D_MODEL + h * DKH;
    #pragma unroll
    for (int reg = 0; reg < 4; ++reg) {
        float inv = 1.f / __shfl(den, 4 * lg + reg, 64);
        #pragma unroll
        for (int sub = 0; sub < 4; ++sub)
            Out[obase + (size_t)reg * D_MODEL + sub * 16 + lr] = o[sub][reg] * inv;
    }
#undef STAGE_KV
}

extern "C" void kernel_launch(void* const* d_in, const int* in_sizes, int n_in,
                              void* d_out, int out_size, void* d_ws, size_t ws_size,
                              hipStream_t stream) {
    const float* x   = (const float*)d_in[0];
    const float* z_q = (const float*)d_in[1];
    const float* b_q = (const float*)d_in[2];
    const float* z_k = (const float*)d_in[3];
    const float* b_k = (const float*)d_in[4];
    const float* w_v = (const float*)d_in[5];
    const float* b_v = (const float*)d_in[6];
    float* out = (float*)d_out;

    // ws (~86MB): Pf fp32 32MB (VT bf16 16MB aliases first half after Pf dies)
    //   | xb 16MB | zqT 2MB | zkT 2MB | wvb 2MB | Qb 16MB | Kb 16MB | aux
    float*  Pf  = (float*)d_ws;
    ushort* VT  = (ushort*)Pf;                       // written after Pf is dead
    ushort* xb  = (ushort*)(Pf + NELEM);
    ushort* zqT = xb + NELEM;
    ushort* zkT = zqT + (size_t)D_MODEL * D_MODEL;
    ushort* wvb = zkT + (size_t)D_MODEL * D_MODEL;
    ushort* Qb  = wvb + (size_t)D_MODEL * D_MODEL;
    ushort* Kb  = Qb + NELEM;
    float*  aux = (float*)(Kb + NELEM);
    float* znq = aux;        float* chq = aux + 1024; float* shq = aux + 2048;
    float* znk = aux + 3072; float* chk = aux + 4096; float* shk = aux + 5120;
    float* lam = aux + 6144;  // 8192 floats

    prep_kernel<<<dim3(1024), 256, 0, stream>>>(z_q, b_q, znq, chq, shq);
    prep_kernel<<<dim3(1024), 256, 0, stream>>>(z_k, b_k, znk, chk, shk);

    cast_x_lam<<<dim3(NTOK), 256, 0, stream>>>(x, xb, lam);
    cast_transpose_bf16<<<dim3(16, 16), 256, 0, stream>>>(z_q, zqT);
    cast_transpose_bf16<<<dim3(16, 16), 256, 0, stream>>>(z_k, zkT);
    cast_bf16<<<dim3(D_MODEL * D_MODEL / 8 / 256), 256, 0, stream>>>(w_v, wvb);

    // Q chain (scale log2(e)/8 folded into bf16 Q)
    gemm_bf16<0><<<dim3(8, 64), 256, 0, stream>>>(xb, zqT, nullptr, Pf);
    poincare_epilogue<<<dim3(NTOK), 256, 0, stream>>>(Pf, lam, znq, chq, shq, Qb, 0.1803368801f);
    // K chain (reuses Pf)
    gemm_bf16<0><<<dim3(8, 64), 256, 0, stream>>>(xb, zkT, nullptr, Pf);
    poincare_epilogue<<<dim3(NTOK), 256, 0, stream>>>(Pf, lam, znk, chk, shk, Kb, 1.0f);
    // V chain: bias + direct transposed VT[b,h,dk,s] write (Pf dead -> aliased)
    gemm_bf16<2><<<dim3(8, 64), 256, 0, stream>>>(xb, wvb, b_v, VT);

    attn_mfma<<<dim3(1024), 512, 0, stream>>>(Qb, Kb, VT, out);
}